// Round 2
// baseline (8046.045 us; speedup 1.0000x reference)
//
#include <hip/hip_runtime.h>
#include <float.h>

#define NB 64
#define HD 1024
#define KG 256          // HD/4 float4 k-groups
#define H3 3072
#define NC6 6144        // 2*3H (gi cols 0..3071, gh cols 3072..6143)
#define NV 32000
#define TSTEPS 32
#define LBLK 500        // logits blocks (64 cols each)

__device__ __forceinline__ float sigmoidf_(float x) {
    return 1.0f / (1.0f + expf(-x));
}

// T4 layout: float4 T4[kg][b] (kg = k>>2, b = batch), flat index kg*NB + b.

// ---------------- init: h0 = [zs|cs], x0 = emb[SOS=1] ----------------
__global__ __launch_bounds__(256) void init_kernel(
    const float* __restrict__ zs, const float* __restrict__ cs,
    const float* __restrict__ emb, float* __restrict__ h,
    float4* __restrict__ Ht4, float4* __restrict__ Xt4)
{
    int b = blockIdx.x;
    int j = threadIdx.x * 4;      // k base, threadIdx.x = kg
    float4 v;
    if (j < 512) v = *(const float4*)&zs[b * 512 + j];
    else         v = *(const float4*)&cs[b * 512 + (j - 512)];
    *(float4*)&h[b * HD + j] = v;
    Ht4[threadIdx.x * NB + b] = v;
    Xt4[threadIdx.x * NB + b] = *(const float4*)&emb[1 * HD + j];  // SOS = 1
}

// ---------------- gates GEMV: gpart[ks][c][b] partials ----------------
// grid 384: cg = blk>>1 (192 col-groups of 32), ks = blk&1 (K half).
// 4 waves x 8 cols/wave. lane = batch. W rows via wave-uniform scalar loads.
__global__ __launch_bounds__(256) void gates_gemv(
    const float4* __restrict__ Xt4, const float4* __restrict__ Ht4,
    const float* __restrict__ Wih, const float* __restrict__ Whh,
    float* __restrict__ gpart)
{
    int cg = blockIdx.x >> 1;
    int ks = blockIdx.x & 1;
    int c0 = cg * 32;                       // global col base (0..6143)
    bool isH = (c0 >= H3);
    const float4* __restrict__ T4 = isH ? Ht4 : Xt4;
    const float* __restrict__ W   = isH ? Whh : Wih;

    int tid = threadIdx.x, wid = tid >> 6, lane = tid & 63;
    int cw = c0 + wid * 8;
    int cu = __builtin_amdgcn_readfirstlane(cw - (isH ? H3 : 0));
    const float* __restrict__ wb = W + (size_t)cu * HD + ks * (HD / 2);

    __shared__ float4 sT[4096];             // 64 kg x 64 b = 64 KB

    float acc[8] = {};
    for (int ch = 0; ch < 2; ++ch) {
        int kg0 = ks * 128 + ch * 64;
        __syncthreads();
        #pragma unroll
        for (int i = 0; i < 16; ++i)
            sT[i * 256 + tid] = T4[kg0 * NB + i * 256 + tid];
        __syncthreads();
        for (int kg = 0; kg < 64; ++kg) {
            float4 hv = sT[kg * NB + lane];
            #pragma unroll
            for (int r = 0; r < 8; ++r) {
                float4 wv = *(const float4*)(wb + (size_t)r * HD + ch * 256 + kg * 4);
                acc[r] = fmaf(hv.w, wv.w, fmaf(hv.z, wv.z,
                         fmaf(hv.y, wv.y, fmaf(hv.x, wv.x, acc[r]))));
            }
        }
    }
    #pragma unroll
    for (int r = 0; r < 8; ++r)
        gpart[((size_t)ks * NC6 + cw + r) * NB + lane] = acc[r];
}

// ---------------- GRU gate fusion: h = (1-z)*n + z*h; writes h + Ht4 ----------------
__global__ __launch_bounds__(256) void gru_fuse(
    const float* __restrict__ gpart,
    const float* __restrict__ bih, const float* __restrict__ bhh,
    float* __restrict__ h, float4* __restrict__ Ht4)
{
    int b = blockIdx.x;
    int j0 = threadIdx.x * 4;
    float out[4];
    #pragma unroll
    for (int u = 0; u < 4; ++u) {
        int j = j0 + u;
        float ir = gpart[(size_t)(j) * NB + b]        + gpart[((size_t)NC6 + j) * NB + b]        + bih[j];
        float iz = gpart[(size_t)(HD + j) * NB + b]   + gpart[((size_t)NC6 + HD + j) * NB + b]   + bih[HD + j];
        float in_= gpart[(size_t)(2*HD + j) * NB + b] + gpart[((size_t)NC6 + 2*HD + j) * NB + b] + bih[2*HD + j];
        float hr = gpart[(size_t)(H3 + j) * NB + b]        + gpart[((size_t)NC6 + H3 + j) * NB + b]        + bhh[j];
        float hz = gpart[(size_t)(H3 + HD + j) * NB + b]   + gpart[((size_t)NC6 + H3 + HD + j) * NB + b]   + bhh[HD + j];
        float hn = gpart[(size_t)(H3 + 2*HD + j) * NB + b] + gpart[((size_t)NC6 + H3 + 2*HD + j) * NB + b] + bhh[2*HD + j];
        float r = sigmoidf_(ir + hr);
        float z = sigmoidf_(iz + hz);
        float n = tanhf(in_ + r * hn);
        float hv = h[(size_t)b * HD + j];
        out[u] = (1.0f - z) * n + z * hv;
    }
    *(float4*)&h[(size_t)b * HD + j0] = make_float4(out[0], out[1], out[2], out[3]);
    Ht4[(j0 >> 2) * NB + b] = make_float4(out[0], out[1], out[2], out[3]);
}

// ---------------- logits GEMV + per-block argmax ----------------
// grid 500, 64 cols/block, 4 waves x 16 cols/wave, lane = batch.
__global__ __launch_bounds__(256) void logits_gemv(
    const float4* __restrict__ Ht4, const float* __restrict__ Wout,
    const float* __restrict__ bout,
    float* __restrict__ bval, int* __restrict__ bidx)
{
    int c0 = blockIdx.x * 64;
    int tid = threadIdx.x, wid = tid >> 6, lane = tid & 63;
    int cw = c0 + wid * 16;
    int cu = __builtin_amdgcn_readfirstlane(cw);
    const float* __restrict__ wb = Wout + (size_t)cu * HD;

    __shared__ float4 sT[4096];             // 64 kg x 64 b = 64 KB

    float acc[16] = {};
    for (int ch = 0; ch < 4; ++ch) {
        __syncthreads();
        #pragma unroll
        for (int i = 0; i < 16; ++i)
            sT[i * 256 + tid] = Ht4[ch * 4096 + i * 256 + tid];
        __syncthreads();
        for (int kg = 0; kg < 64; ++kg) {
            float4 hv = sT[kg * NB + lane];
            #pragma unroll
            for (int r = 0; r < 16; ++r) {
                float4 wv = *(const float4*)(wb + (size_t)r * HD + ch * 256 + kg * 4);
                acc[r] = fmaf(hv.w, wv.w, fmaf(hv.z, wv.z,
                         fmaf(hv.y, wv.y, fmaf(hv.x, wv.x, acc[r]))));
            }
        }
    }

    // bias + in-register argmax (cols ascending -> first-max tie-break)
    float bv = -FLT_MAX; int bi = 0x7fffffff;
    #pragma unroll
    for (int r = 0; r < 16; ++r) {
        float v = acc[r] + bout[cw + r];
        if (v > bv) { bv = v; bi = cw + r; }
    }
    // cross-wave combine via LDS (reuse sT)
    float* sv = (float*)sT;
    int*   si = (int*)(sv + 256);
    __syncthreads();
    sv[wid * 64 + lane] = bv;
    si[wid * 64 + lane] = bi;
    __syncthreads();
    if (wid == 0) {
        #pragma unroll
        for (int w = 1; w < 4; ++w) {
            float ov = sv[w * 64 + lane];
            int   oi = si[w * 64 + lane];
            if (ov > bv || (ov == bv && oi < bi)) { bv = ov; bi = oi; }
        }
        bval[(size_t)lane * LBLK + blockIdx.x] = bv;   // lane = batch
        bidx[(size_t)lane * LBLK + blockIdx.x] = bi;
    }
}

// ---------------- argmax reduce across 500 blocks + embedding gather ----------------
__global__ __launch_bounds__(512) void argmax_reduce_gather(
    const float* __restrict__ bval, const int* __restrict__ bidx,
    const float* __restrict__ emb, int* __restrict__ resps, int t,
    float4* __restrict__ Xt4)
{
    int b = blockIdx.x;
    int tid = threadIdx.x;
    float bv = -FLT_MAX; int bi = 0x7fffffff;
    if (tid < LBLK) { bv = bval[(size_t)b * LBLK + tid]; bi = bidx[(size_t)b * LBLK + tid]; }
    for (int off = 32; off > 0; off >>= 1) {
        float ov = __shfl_down(bv, off);
        int   oi = __shfl_down(bi, off);
        if (ov > bv || (ov == bv && oi < bi)) { bv = ov; bi = oi; }
    }
    __shared__ float sv[8];
    __shared__ int   si[8];
    __shared__ int   stok;
    int wid = tid >> 6;
    if ((tid & 63) == 0) { sv[wid] = bv; si[wid] = bi; }
    __syncthreads();
    if (tid == 0) {
        bv = sv[0]; bi = si[0];
        #pragma unroll
        for (int w = 1; w < 8; ++w)
            if (sv[w] > bv || (sv[w] == bv && si[w] < bi)) { bv = sv[w]; bi = si[w]; }
        stok = bi;
        resps[b * TSTEPS + t] = bi;
    }
    __syncthreads();
    if (tid < 256) {
        int tok = stok;
        Xt4[tid * NB + b] = *(const float4*)&emb[(size_t)tok * HD + tid * 4];
    }
}

// ---------------- resp_lens ----------------
__global__ void resp_lens_kernel(const int* __restrict__ resps, int* __restrict__ lens)
{
    int b = threadIdx.x;
    if (b >= NB) return;
    int len = TSTEPS + 1;
    for (int t = TSTEPS - 1; t >= 0; t--)
        if (resps[b * TSTEPS + t] == 2) len = t + 1;
    lens[b] = len;
}

extern "C" void kernel_launch(void* const* d_in, const int* in_sizes, int n_in,
                              void* d_out, int out_size, void* d_ws, size_t ws_size,
                              hipStream_t stream) {
    const float* zs   = (const float*)d_in[0];
    const float* cs   = (const float*)d_in[1];
    const float* emb  = (const float*)d_in[2];
    const float* Wih  = (const float*)d_in[3];
    const float* Whh  = (const float*)d_in[4];
    const float* bih  = (const float*)d_in[5];
    const float* bhh  = (const float*)d_in[6];
    const float* Wout = (const float*)d_in[7];
    const float* bout = (const float*)d_in[8];
    int* out = (int*)d_out;  // [64*32 resps][64 lens], int32

    char* ws = (char*)d_ws;
    float4* Xt4 = (float4*)ws; ws += (size_t)KG * NB * 16;        // 256 KB
    float4* Ht4 = (float4*)ws; ws += (size_t)KG * NB * 16;        // 256 KB
    float*  h   = (float*)ws;  ws += (size_t)NB * HD * 4;         // 256 KB
    float*  gpart = (float*)ws; ws += (size_t)2 * NC6 * NB * 4;   // 3 MB
    float*  bval = (float*)ws; ws += (size_t)NB * LBLK * 4;       // 125 KB
    int*    bidx = (int*)ws;   ws += (size_t)NB * LBLK * 4;       // 125 KB

    init_kernel<<<NB, 256, 0, stream>>>(zs, cs, emb, h, Ht4, Xt4);
    for (int t = 0; t < TSTEPS; t++) {
        gates_gemv<<<384, 256, 0, stream>>>(Xt4, Ht4, Wih, Whh, gpart);
        gru_fuse<<<NB, 256, 0, stream>>>(gpart, bih, bhh, h, Ht4);
        logits_gemv<<<LBLK, 256, 0, stream>>>(Ht4, Wout, bout, bval, bidx);
        argmax_reduce_gather<<<NB, 512, 0, stream>>>(bval, bidx, emb, out, t, Xt4);
    }
    resp_lens_kernel<<<1, 64, 0, stream>>>(out, out + NB * TSTEPS);
}

// Round 3
// 4790.385 us; speedup vs baseline: 1.6796x; 1.6796x over previous
//
#include <hip/hip_runtime.h>
#include <float.h>

#define NB 64
#define HD 1024
#define H3 3072
#define NC6 6144
#define NV 32000
#define TSTEPS 32
#define LBLK 500        // logits blocks (64 cols each)
#define GKS 4           // gates K-split

__device__ __forceinline__ float sigmoidf_(float x) {
    return 1.0f / (1.0f + expf(-x));
}

// ---------------- init: h0 = [zs|cs], x0 = emb[SOS=1] ----------------
__global__ __launch_bounds__(256) void init_kernel(
    const float* __restrict__ zs, const float* __restrict__ cs,
    const float* __restrict__ emb, float* __restrict__ h, float* __restrict__ x)
{
    int b = blockIdx.x;
    int j = threadIdx.x * 4;
    float4 v;
    if (j < 512) v = *(const float4*)&zs[b * 512 + j];
    else         v = *(const float4*)&cs[b * 512 + (j - 512)];
    *(float4*)&h[(size_t)b * HD + j] = v;
    *(float4*)&x[(size_t)b * HD + j] = *(const float4*)&emb[HD + j];  // SOS = 1
}

// ============ shared GEMM template (64 batch x 64 cols, Ktiles of 64) ============
// lane = ch*32 + bl: batches bl, bl+32; cols cbase = c0 + wid*16 + ch*8 .. +7.
// H staged swizzled (granule b*16 + (kg^(b&15))), W staged linear (broadcast reads).

// ---------------- logits + per-block argmax ----------------
__global__ __launch_bounds__(256) void logits_gemv(
    const float* __restrict__ hsrc, const float* __restrict__ Wout,
    const float* __restrict__ bout,
    float* __restrict__ bval, int* __restrict__ bidx)
{
    int c0 = blockIdx.x * 64;
    int tid = threadIdx.x;
    int wid = tid >> 6, lane = tid & 63;
    int bl = lane & 31, ch = lane >> 5;
    int m0 = bl & 15;

    __shared__ float4 Hs[64 * 16];
    __shared__ float4 Ws[64 * 16];
    __shared__ float  sv[64][8];
    __shared__ int    si[64][8];

    float4 pw[4], ph[4];
    #pragma unroll
    for (int i = 0; i < 4; ++i) {
        int fi = tid + i * 256;
        int r = fi >> 4, kg = fi & 15;
        pw[i] = *(const float4*)&Wout[(size_t)(c0 + r) * HD + kg * 4];
        ph[i] = *(const float4*)&hsrc[(size_t)r * HD + kg * 4];
    }
    float acc0[8] = {}, acc1[8] = {};

    for (int kt = 0; kt < 16; ++kt) {
        __syncthreads();
        #pragma unroll
        for (int i = 0; i < 4; ++i) {
            int fi = tid + i * 256;
            int r = fi >> 4, kg = fi & 15;
            Ws[r * 16 + kg] = pw[i];
            Hs[r * 16 + (kg ^ (r & 15))] = ph[i];
        }
        __syncthreads();
        if (kt < 15) {
            int k0 = (kt + 1) * 64;
            #pragma unroll
            for (int i = 0; i < 4; ++i) {
                int fi = tid + i * 256;
                int r = fi >> 4, kg = fi & 15;
                pw[i] = *(const float4*)&Wout[(size_t)(c0 + r) * HD + k0 + kg * 4];
                ph[i] = *(const float4*)&hsrc[(size_t)r * HD + k0 + kg * 4];
            }
        }
        int wbase = (wid * 16 + ch * 8) * 16;
        #pragma unroll
        for (int kg = 0; kg < 16; ++kg) {
            float4 h0 = Hs[bl * 16 + (kg ^ m0)];
            float4 h1 = Hs[(bl + 32) * 16 + (kg ^ m0)];
            #pragma unroll
            for (int r = 0; r < 8; ++r) {
                float4 wv = Ws[wbase + r * 16 + kg];
                acc0[r] = fmaf(h0.w, wv.w, fmaf(h0.z, wv.z, fmaf(h0.y, wv.y, fmaf(h0.x, wv.x, acc0[r]))));
                acc1[r] = fmaf(h1.w, wv.w, fmaf(h1.z, wv.z, fmaf(h1.y, wv.y, fmaf(h1.x, wv.x, acc1[r]))));
            }
        }
    }

    int cbase = c0 + wid * 16 + ch * 8;
    float bv0 = -FLT_MAX, bv1 = -FLT_MAX; int bi0 = 0, bi1 = 0;
    #pragma unroll
    for (int r = 0; r < 8; ++r) {
        float bo = bout[cbase + r];
        float v0 = acc0[r] + bo;
        float v1 = acc1[r] + bo;
        if (v0 > bv0) { bv0 = v0; bi0 = cbase + r; }
        if (v1 > bv1) { bv1 = v1; bi1 = cbase + r; }
    }
    __syncthreads();
    int slot = wid * 2 + ch;
    sv[bl][slot] = bv0;      si[bl][slot] = bi0;
    sv[bl + 32][slot] = bv1; si[bl + 32][slot] = bi1;
    __syncthreads();
    if (wid == 0) {
        float bv = sv[lane][0]; int bi = si[lane][0];
        #pragma unroll
        for (int s = 1; s < 8; ++s) {
            float v = sv[lane][s];
            if (v > bv) { bv = v; bi = si[lane][s]; }   // slots ascend in col -> first-max
        }
        bval[(size_t)lane * LBLK + blockIdx.x] = bv;
        bidx[(size_t)lane * LBLK + blockIdx.x] = bi;
    }
}

// ---------------- gates GEMV, K-split 4, partials gpart[ks][b][6144] ----------------
__global__ __launch_bounds__(256) void gates_gemv(
    const float* __restrict__ x, const float* __restrict__ hsrc,
    const float* __restrict__ Wih, const float* __restrict__ Whh,
    float* __restrict__ gpart)
{
    int cg = blockIdx.x >> 2;       // 0..95
    int ks = blockIdx.x & 3;
    int c0 = cg * 64;               // 0..6143
    bool isH = c0 >= H3;
    const float* __restrict__ src = isH ? hsrc : x;
    const float* __restrict__ W   = isH ? Whh : Wih;
    int wc0 = c0 - (isH ? H3 : 0);
    int k00 = ks * 256;

    int tid = threadIdx.x;
    int wid = tid >> 6, lane = tid & 63;
    int bl = lane & 31, ch = lane >> 5;
    int m0 = bl & 15;

    __shared__ float4 Hs[64 * 16];
    __shared__ float4 Ws[64 * 16];

    float4 pw[4], ph[4];
    #pragma unroll
    for (int i = 0; i < 4; ++i) {
        int fi = tid + i * 256;
        int r = fi >> 4, kg = fi & 15;
        pw[i] = *(const float4*)&W[(size_t)(wc0 + r) * HD + k00 + kg * 4];
        ph[i] = *(const float4*)&src[(size_t)r * HD + k00 + kg * 4];
    }
    float acc0[8] = {}, acc1[8] = {};

    for (int kt = 0; kt < 4; ++kt) {
        __syncthreads();
        #pragma unroll
        for (int i = 0; i < 4; ++i) {
            int fi = tid + i * 256;
            int r = fi >> 4, kg = fi & 15;
            Ws[r * 16 + kg] = pw[i];
            Hs[r * 16 + (kg ^ (r & 15))] = ph[i];
        }
        __syncthreads();
        if (kt < 3) {
            int k0 = k00 + (kt + 1) * 64;
            #pragma unroll
            for (int i = 0; i < 4; ++i) {
                int fi = tid + i * 256;
                int r = fi >> 4, kg = fi & 15;
                pw[i] = *(const float4*)&W[(size_t)(wc0 + r) * HD + k0 + kg * 4];
                ph[i] = *(const float4*)&src[(size_t)r * HD + k0 + kg * 4];
            }
        }
        int wbase = (wid * 16 + ch * 8) * 16;
        #pragma unroll
        for (int kg = 0; kg < 16; ++kg) {
            float4 h0 = Hs[bl * 16 + (kg ^ m0)];
            float4 h1 = Hs[(bl + 32) * 16 + (kg ^ m0)];
            #pragma unroll
            for (int r = 0; r < 8; ++r) {
                float4 wv = Ws[wbase + r * 16 + kg];
                acc0[r] = fmaf(h0.w, wv.w, fmaf(h0.z, wv.z, fmaf(h0.y, wv.y, fmaf(h0.x, wv.x, acc0[r]))));
                acc1[r] = fmaf(h1.w, wv.w, fmaf(h1.z, wv.z, fmaf(h1.y, wv.y, fmaf(h1.x, wv.x, acc1[r]))));
            }
        }
    }
    int cbase = c0 + wid * 16 + ch * 8;
    float* g0 = gpart + (size_t)(ks * NB + bl) * NC6 + cbase;
    float* g1 = gpart + (size_t)(ks * NB + bl + 32) * NC6 + cbase;
    *(float4*)(g0)     = make_float4(acc0[0], acc0[1], acc0[2], acc0[3]);
    *(float4*)(g0 + 4) = make_float4(acc0[4], acc0[5], acc0[6], acc0[7]);
    *(float4*)(g1)     = make_float4(acc1[0], acc1[1], acc1[2], acc1[3]);
    *(float4*)(g1 + 4) = make_float4(acc1[4], acc1[5], acc1[6], acc1[7]);
}

// ---------------- GRU gate fusion ----------------
__global__ __launch_bounds__(256) void gru_fuse(
    const float* __restrict__ gpart,
    const float* __restrict__ bih, const float* __restrict__ bhh,
    float* __restrict__ h)
{
    int b = blockIdx.x;
    int j0 = threadIdx.x * 4;
    float4 ir = {}, iz = {}, in_ = {}, hr = {}, hz = {}, hn = {};
    #pragma unroll
    for (int ks = 0; ks < GKS; ++ks) {
        const float* g = gpart + (size_t)(ks * NB + b) * NC6;
        float4 a;
        a = *(const float4*)&g[j0];           ir.x += a.x; ir.y += a.y; ir.z += a.z; ir.w += a.w;
        a = *(const float4*)&g[HD + j0];      iz.x += a.x; iz.y += a.y; iz.z += a.z; iz.w += a.w;
        a = *(const float4*)&g[2*HD + j0];    in_.x += a.x; in_.y += a.y; in_.z += a.z; in_.w += a.w;
        a = *(const float4*)&g[H3 + j0];      hr.x += a.x; hr.y += a.y; hr.z += a.z; hr.w += a.w;
        a = *(const float4*)&g[H3 + HD + j0]; hz.x += a.x; hz.y += a.y; hz.z += a.z; hz.w += a.w;
        a = *(const float4*)&g[H3 + 2*HD + j0]; hn.x += a.x; hn.y += a.y; hn.z += a.z; hn.w += a.w;
    }
    float4 vbi0 = *(const float4*)&bih[j0];
    float4 vbi1 = *(const float4*)&bih[HD + j0];
    float4 vbi2 = *(const float4*)&bih[2*HD + j0];
    float4 vbh0 = *(const float4*)&bhh[j0];
    float4 vbh1 = *(const float4*)&bhh[HD + j0];
    float4 vbh2 = *(const float4*)&bhh[2*HD + j0];
    float4 hv = *(const float4*)&h[(size_t)b * HD + j0];
    float o[4];
    float irv[4] = {ir.x+vbi0.x, ir.y+vbi0.y, ir.z+vbi0.z, ir.w+vbi0.w};
    float izv[4] = {iz.x+vbi1.x, iz.y+vbi1.y, iz.z+vbi1.z, iz.w+vbi1.w};
    float inv[4] = {in_.x+vbi2.x, in_.y+vbi2.y, in_.z+vbi2.z, in_.w+vbi2.w};
    float hrv[4] = {hr.x+vbh0.x, hr.y+vbh0.y, hr.z+vbh0.z, hr.w+vbh0.w};
    float hzv[4] = {hz.x+vbh1.x, hz.y+vbh1.y, hz.z+vbh1.z, hz.w+vbh1.w};
    float hnv[4] = {hn.x+vbh2.x, hn.y+vbh2.y, hn.z+vbh2.z, hn.w+vbh2.w};
    float hvv[4] = {hv.x, hv.y, hv.z, hv.w};
    #pragma unroll
    for (int u = 0; u < 4; ++u) {
        float r = sigmoidf_(irv[u] + hrv[u]);
        float z = sigmoidf_(izv[u] + hzv[u]);
        float n = tanhf(inv[u] + r * hnv[u]);
        o[u] = (1.0f - z) * n + z * hvv[u];
    }
    *(float4*)&h[(size_t)b * HD + j0] = make_float4(o[0], o[1], o[2], o[3]);
}

// ---------------- argmax reduce across 500 blocks + embedding gather ----------------
__global__ __launch_bounds__(512) void argmax_reduce_gather(
    const float* __restrict__ bval, const int* __restrict__ bidx,
    const float* __restrict__ emb, int* __restrict__ resps, int t,
    float* __restrict__ x)
{
    int b = blockIdx.x;
    int tid = threadIdx.x;
    float bv = -FLT_MAX; int bi = 0x7fffffff;
    if (tid < LBLK) { bv = bval[(size_t)b * LBLK + tid]; bi = bidx[(size_t)b * LBLK + tid]; }
    for (int off = 32; off > 0; off >>= 1) {
        float ov = __shfl_down(bv, off);
        int   oi = __shfl_down(bi, off);
        if (ov > bv || (ov == bv && oi < bi)) { bv = ov; bi = oi; }
    }
    __shared__ float sv[8];
    __shared__ int   si[8];
    __shared__ int   stok;
    int wid = tid >> 6;
    if ((tid & 63) == 0) { sv[wid] = bv; si[wid] = bi; }
    __syncthreads();
    if (tid == 0) {
        bv = sv[0]; bi = si[0];
        #pragma unroll
        for (int w = 1; w < 8; ++w)
            if (sv[w] > bv || (sv[w] == bv && si[w] < bi)) { bv = sv[w]; bi = si[w]; }
        stok = bi;
        resps[b * TSTEPS + t] = bi;
    }
    __syncthreads();
    if (tid < 256) {
        int tok = stok;
        *(float4*)&x[(size_t)b * HD + tid * 4] =
            *(const float4*)&emb[(size_t)tok * HD + tid * 4];
    }
}

// ---------------- resp_lens ----------------
__global__ void resp_lens_kernel(const int* __restrict__ resps, int* __restrict__ lens)
{
    int b = threadIdx.x;
    if (b >= NB) return;
    int len = TSTEPS + 1;
    for (int t = TSTEPS - 1; t >= 0; t--)
        if (resps[b * TSTEPS + t] == 2) len = t + 1;
    lens[b] = len;
}

extern "C" void kernel_launch(void* const* d_in, const int* in_sizes, int n_in,
                              void* d_out, int out_size, void* d_ws, size_t ws_size,
                              hipStream_t stream) {
    const float* zs   = (const float*)d_in[0];
    const float* cs   = (const float*)d_in[1];
    const float* emb  = (const float*)d_in[2];
    const float* Wih  = (const float*)d_in[3];
    const float* Whh  = (const float*)d_in[4];
    const float* bih  = (const float*)d_in[5];
    const float* bhh  = (const float*)d_in[6];
    const float* Wout = (const float*)d_in[7];
    const float* bout = (const float*)d_in[8];
    int* out = (int*)d_out;  // [64*32 resps][64 lens], int32

    char* ws = (char*)d_ws;
    float* x     = (float*)ws; ws += (size_t)NB * HD * 4;             // 256 KB
    float* h     = (float*)ws; ws += (size_t)NB * HD * 4;             // 256 KB
    float* gpart = (float*)ws; ws += (size_t)GKS * NB * NC6 * 4;      // 6.3 MB
    float* bval  = (float*)ws; ws += (size_t)NB * LBLK * 4;           // 128 KB
    int*   bidx  = (int*)ws;   ws += (size_t)NB * LBLK * 4;           // 128 KB

    init_kernel<<<NB, 256, 0, stream>>>(zs, cs, emb, h, x);
    for (int t = 0; t < TSTEPS; t++) {
        gates_gemv<<<96 * GKS, 256, 0, stream>>>(x, h, Wih, Whh, gpart);
        gru_fuse<<<NB, 256, 0, stream>>>(gpart, bih, bhh, h);
        logits_gemv<<<LBLK, 256, 0, stream>>>(h, Wout, bout, bval, bidx);
        argmax_reduce_gather<<<NB, 512, 0, stream>>>(bval, bidx, emb, out, t, x);
    }
    resp_lens_kernel<<<1, 64, 0, stream>>>(out, out + NB * TSTEPS);
}